// Round 6
// baseline (375.768 us; speedup 1.0000x reference)
//
#include <hip/hip_runtime.h>
#include <hip/hip_bf16.h>
#include <stdint.h>

typedef unsigned short u16;
typedef u16 u16x4 __attribute__((ext_vector_type(4)));
typedef short bf16x8 __attribute__((ext_vector_type(8)));
typedef float f32x4 __attribute__((ext_vector_type(4)));

__device__ __forceinline__ u16 f2bf(float f) {
  union { float f; uint32_t u; } v; v.f = f;
  uint32_t u = v.u;
  return (u16)((u + 0x7fffu + ((u >> 16) & 1u)) >> 16);
}

// ---------------- fused aux: x fp32->bf16  +  W_eff = W + 2*(B@A) -> bf16 ----------------
__global__ __launch_bounds__(256) void aux_kernel(
    const float4* __restrict__ x, u16x4* __restrict__ xb, int n4, int nCvt,
    const float* __restrict__ W, const float* __restrict__ A,
    const float* __restrict__ Bl, u16* __restrict__ Wout, int DIN) {
  if ((int)blockIdx.x < nCvt) {
    int i = blockIdx.x * 256 + threadIdx.x;
    const int stride = nCvt * 256;
    for (; i < n4; i += stride) {
      float4 v = x[i];
      u16x4 o;
      o.x = f2bf(v.x); o.y = f2bf(v.y); o.z = f2bf(v.z); o.w = f2bf(v.w);
      xb[i] = o;
    }
  } else {
    const int n = blockIdx.x - nCvt;
    float bv[16];
#pragma unroll
    for (int r = 0; r < 16; ++r) bv[r] = 2.0f * Bl[n * 16 + r];
    const int iters = DIN / (256 * 4);
    for (int c = 0; c < iters; ++c) {
      const int k = (c * 256 + (int)threadIdx.x) * 4;
      float4 wv = *(const float4*)&W[(size_t)n * DIN + k];
#pragma unroll
      for (int r = 0; r < 16; ++r) {
        const float4 av = *(const float4*)&A[(size_t)r * DIN + k];
        wv.x += bv[r] * av.x;
        wv.y += bv[r] * av.y;
        wv.z += bv[r] * av.z;
        wv.w += bv[r] * av.w;
      }
      u16x4 o;
      o.x = f2bf(wv.x); o.y = f2bf(wv.y); o.z = f2bf(wv.z); o.w = f2bf(wv.w);
      *(u16x4*)&Wout[(size_t)n * DIN + k] = o;
    }
  }
}

// ---------------- 256x128 TLP bf16 GEMM, ring-3 counted-vmcnt ----------------
// C[M][N] = X[M][K] @ Weff[N][K]^T + bias
// Tile 256x128, 8 waves (4M x 2N, 64x64 out each). LDS = ring of 3 slabs,
// slab = A[256][32] (16 KB) + B[128][32] (8 KB) = 24 KB; total 72 KiB ->
// 2 blocks/CU (16 waves = 4/SIMD) for TLP overlap of LDS reads with MFMA.
// Per slab: {vmcnt(3); barrier; stage slab s+2 (3 gloads/wave); read 8 frags;
// 16 MFMA}. vmcnt(3) retires exactly slab s's ops (issued 2 slabs earlier);
// slab s+1's 3 ops stay in flight (T4: never drain to 0 in the loop).
// Stage writes slot (s+2)%3 whose last reads (slab s-1) completed before this
// barrier -> race-free. Wrap-staging (kt=0 junk) keeps vmcnt count uniform;
// junk slots are never read again. Swizzle = r2's proven 0-conflict pattern.
#define BM 256
#define BN 128

__global__ __launch_bounds__(512, 4) void gemm_kernel(
    const u16* __restrict__ A, const u16* __restrict__ B,
    const float* __restrict__ bias, float* __restrict__ C,
    int M, int N, int K) {
  extern __shared__ u16 lds[];   // 73728 bytes = 3 slabs x 12288 u16

  const int tid  = threadIdx.x;
  const int lane = tid & 63;
  const int wid  = tid >> 6;

  // XCD-aware block swizzle (nwg % 8 == 0 by launch)
  const int nwg = gridDim.x;
  const int cpx = nwg >> 3;
  const int f   = ((int)blockIdx.x & 7) * cpx + ((int)blockIdx.x >> 3);
  const int nbx = N / BN;
  const int bx = f % nbx, by = f / nbx;
  const int bm = by * BM, bn = bx * BN;

  const int wm = (wid >> 1) * 64;   // 4 M-wave rows
  const int wn = (wid & 1) * 64;    // 2 N-wave cols
  const int lr = lane & 15;
  const int lk = lane >> 4;
  const int rslot = ((lk ^ ((lr >> 1) & 3)) << 3);  // swizzled k-slot (u16)

  // staging: linear LDS dest, pre-swizzled global source (rule #21; r2-proven).
  // srow = tid>>2 spans 0..127 across the block; A issue i adds +128*i rows.
  const int srow  = tid >> 2;
  const int sslot = (((tid & 3) ^ ((tid >> 3) & 3)) << 3);
  const u16* gA = A + (size_t)(bm + srow) * K + sslot;
  const u16* gB = B + (size_t)(bn + srow) * K + sslot;

  // slab layout (u16 offsets within a slab): A at 0..8192, B at 8192..12288
  auto stage = [&](int sb /*slab base, u16*/, int kt /*k-slab index*/) {
    const u16* sa = gA + (size_t)kt * 32;
#pragma unroll
    for (int i = 0; i < 2; ++i)
      __builtin_amdgcn_global_load_lds(
          (__attribute__((address_space(1))) const void*)(sa + (size_t)i * 128 * K),
          (__attribute__((address_space(3))) void*)(&lds[sb + wid * 512 + i * 4096]),
          16, 0, 0);
    __builtin_amdgcn_global_load_lds(
        (__attribute__((address_space(1))) const void*)(gB + (size_t)kt * 32),
        (__attribute__((address_space(3))) void*)(&lds[sb + 8192 + wid * 512]),
        16, 0, 0);
  };

  f32x4 acc[4][4];
#pragma unroll
  for (int i = 0; i < 4; ++i)
#pragma unroll
    for (int n = 0; n < 4; ++n) acc[i][n] = f32x4{0.f, 0.f, 0.f, 0.f};

  const int NS = K >> 5;            // 128 slabs of 32 k
  int sb0 = 0, sb1 = 12288, sb2 = 24576;
  stage(sb0, 0);
  stage(sb1, 1);                    // 6 ops in flight

  for (int s = 0; s < NS; ++s) {
    asm volatile("s_waitcnt vmcnt(3)" ::: "memory");  // slab s resident (own 3 ops)
    __builtin_amdgcn_s_barrier();                     // ... for ALL waves
    const int kt = (s + 2 < NS) ? s + 2 : 0;          // wrap keeps count uniform
    stage(sb2, kt);

    bf16x8 b[4], a[4];
#pragma unroll
    for (int n = 0; n < 4; ++n)
      b[n] = *(const bf16x8*)&lds[sb0 + 8192 + (wn + n * 16 + lr) * 32 + rslot];
#pragma unroll
    for (int m = 0; m < 4; ++m)
      a[m] = *(const bf16x8*)&lds[sb0 + (wm + m * 16 + lr) * 32 + rslot];

#pragma unroll
    for (int m = 0; m < 4; ++m)
#pragma unroll
      for (int n = 0; n < 4; ++n)
        acc[m][n] = __builtin_amdgcn_mfma_f32_16x16x32_bf16(a[m], b[n], acc[m][n], 0, 0, 0);

    const int t = sb0; sb0 = sb1; sb1 = sb2; sb2 = t;
  }

  // drain wrapped junk staging DMAs before LDS dealloc / kernel end
  asm volatile("s_waitcnt vmcnt(0)" ::: "memory");
  __builtin_amdgcn_s_barrier();

  // epilogue: C/D layout col = lane&15, row = (lane>>4)*4 + j
#pragma unroll
  for (int nf = 0; nf < 4; ++nf) {
    const int col = bn + wn + nf * 16 + lr;
    const float bv = bias[col];
#pragma unroll
    for (int mf = 0; mf < 4; ++mf) {
      const int row = bm + wm + mf * 16 + lk * 4;
#pragma unroll
      for (int j = 0; j < 4; ++j)
        C[(size_t)(row + j) * N + col] = acc[mf][nf][j] + bv;
    }
  }
}

extern "C" void kernel_launch(void* const* d_in, const int* in_sizes, int n_in,
                              void* d_out, int out_size, void* d_ws, size_t ws_size,
                              hipStream_t stream) {
  const float* x  = (const float*)d_in[0];
  const float* w  = (const float*)d_in[1];
  const float* lA = (const float*)d_in[2];
  const float* lB = (const float*)d_in[3];
  const float* bs = (const float*)d_in[4];
  float* out = (float*)d_out;

  const int DOUT = in_sizes[4];              // 4096
  const int DIN  = in_sizes[1] / DOUT;       // 4096
  const int M    = in_sizes[0] / DIN;        // 8192

  u16* Xb = (u16*)d_ws;                      // M*DIN bf16
  u16* Wb = Xb + (size_t)M * DIN;            // DOUT*DIN bf16

  const int n4 = (M * DIN) / 4;
  const int nCvt = 2048;
  aux_kernel<<<nCvt + DOUT, 256, 0, stream>>>((const float4*)x, (u16x4*)Xb, n4, nCvt,
                                              w, lA, lB, Wb, DIN);

  (void)hipFuncSetAttribute((const void*)gemm_kernel,
                            hipFuncAttributeMaxDynamicSharedMemorySize, 73728);

  const int nwg = (M / BM) * (DOUT / BN);    // 32 * 32 = 1024
  gemm_kernel<<<nwg, 512, 73728, stream>>>(Xb, Wb, bs, out, M, DOUT, DIN);
}

// Round 7
// 373.574 us; speedup vs baseline: 1.0059x; 1.0059x over previous
//
#include <hip/hip_runtime.h>
#include <hip/hip_bf16.h>
#include <stdint.h>

typedef unsigned short u16;
typedef u16 u16x4 __attribute__((ext_vector_type(4)));
typedef u16 u16x8 __attribute__((ext_vector_type(8)));
typedef short bf16x8 __attribute__((ext_vector_type(8)));
typedef float f32x4 __attribute__((ext_vector_type(4)));

__device__ __forceinline__ u16 f2bf(float f) {
  union { float f; uint32_t u; } v; v.f = f;
  uint32_t u = v.u;
  return (u16)((u + 0x7fffu + ((u >> 16) & 1u)) >> 16);
}

// ---------------- fused aux ----------------
// blocks [0, nCvt): x fp32 -> bf16 row-major [M][K]
// blocks [nCvt, ...): W_eff = W + 2*(B@A), emitted in MFMA-FRAG-PACKED layout:
//   frag fid = nf*(K/32) + ks  (nf = col/16, ks = k/32), 1024 B each;
//   lane l of the frag holds W_eff[nf*16 + (l&15)][ks*32 + (l>>4)*8 + e], e=0..7.
// One wave per frag; per-wave A window A[16][32] is L1-resident (kills L2 rereads).
__global__ __launch_bounds__(256) void aux_kernel(
    const float4* __restrict__ x, u16x4* __restrict__ xb, int n4, int nCvt,
    const float* __restrict__ W, const float* __restrict__ A,
    const float* __restrict__ Bl, u16* __restrict__ Wf, int DIN) {
  if ((int)blockIdx.x < nCvt) {
    int i = blockIdx.x * 256 + threadIdx.x;
    const int stride = nCvt * 256;
    for (; i < n4; i += stride) {
      float4 v = x[i];
      u16x4 o;
      o.x = f2bf(v.x); o.y = f2bf(v.y); o.z = f2bf(v.z); o.w = f2bf(v.w);
      xb[i] = o;
    }
  } else {
    const int bb  = (int)blockIdx.x - nCvt;
    const int tid = threadIdx.x;
    const int w   = tid >> 6, l = tid & 63;
    const int KS  = DIN >> 5;              // frags per col-group (128)
    const int fid = bb * 4 + w;            // global frag id
    const int nf  = fid / KS, ks = fid % KS;
    const int col = nf * 16 + (l & 15);
    const int kb  = ks * 32 + ((l >> 4) << 3);

    float4 s0 = *(const float4*)&W[(size_t)col * DIN + kb];
    float4 s1 = *(const float4*)&W[(size_t)col * DIN + kb + 4];
#pragma unroll
    for (int r = 0; r < 16; ++r) {
      const float bv = 2.0f * Bl[col * 16 + r];
      const float4 a0 = *(const float4*)&A[(size_t)r * DIN + kb];
      const float4 a1 = *(const float4*)&A[(size_t)r * DIN + kb + 4];
      s0.x += bv * a0.x; s0.y += bv * a0.y; s0.z += bv * a0.z; s0.w += bv * a0.w;
      s1.x += bv * a1.x; s1.y += bv * a1.y; s1.z += bv * a1.z; s1.w += bv * a1.w;
    }
    u16x8 o;
    o[0] = f2bf(s0.x); o[1] = f2bf(s0.y); o[2] = f2bf(s0.z); o[3] = f2bf(s0.w);
    o[4] = f2bf(s1.x); o[5] = f2bf(s1.y); o[6] = f2bf(s1.z); o[7] = f2bf(s1.w);
    *(u16x8*)&Wf[(size_t)fid * 512 + l * 8] = o;
  }
}

// ---------------- 256x256 bf16 GEMM: A via LDS ring-3, B direct from L2 ----------------
// C[M][N] = X[M][K] @ Weff[N][K]^T + bias.  8 waves (2M x 4N), wave out 128x64.
// Step = 32 k. A slab = [256][32] bf16 = 16 KB, ring of 3 (48 KB LDS, r2-proven swizzle).
// B-frags loaded straight from frag-packed Wf (1 coalesced dwordx4 per frag), double-
// buffered in named reg sets B0/B1, gathered 1 step ahead (L2 latency ~200cy << step).
// Ledger: every step issues exactly 6 vmem (2 stageA for s+2, 4 gathers for s+1);
// vmcnt(6)+barrier at step top retires slab s. Never drains (T4). Wrap keeps count uniform.
#define BM 256
#define BN 256

__global__ __launch_bounds__(512, 2) void gemm_kernel(
    const u16* __restrict__ A, const u16* __restrict__ Bf,
    const float* __restrict__ bias, float* __restrict__ C,
    int M, int N, int K) {
  extern __shared__ u16 lds[];   // 49152 bytes = 3 slabs x 8192 u16

  const int tid  = threadIdx.x;
  const int lane = tid & 63;
  const int wid  = tid >> 6;

  // XCD-aware block swizzle (nwg % 8 == 0 by launch)
  const int nwg = gridDim.x;
  const int cpx = nwg >> 3;
  const int f   = ((int)blockIdx.x & 7) * cpx + ((int)blockIdx.x >> 3);
  const int nbx = N / BN;
  const int bx = f % nbx, by = f / nbx;
  const int bm = by * BM, bn = bx * BN;

  const int wmL = (wid >> 2) * 128;
  const int wnL = (wid & 3) * 64;
  const int lr  = lane & 15;
  const int lk  = lane >> 4;
  const int rslot = ((lk ^ ((lr >> 1) & 3)) << 3);  // swizzled A k-slot (r2-proven)

  // A staging: linear LDS dest, pre-swizzled global source (rule #21)
  const int srow  = tid >> 2;
  const int sslot = (((tid & 3) ^ ((tid >> 3) & 3)) << 3);
  const u16* gA = A + (size_t)(bm + srow) * K + sslot;

  const int NS = K >> 5;                 // 128 steps of 32 k
  const int nfg0 = (bn + wnL) >> 4;      // wave's first global n-frag

  auto stageA = [&](int sb, int kt) {
    const u16* s = gA + (size_t)kt * 32;
#pragma unroll
    for (int i = 0; i < 2; ++i)
      __builtin_amdgcn_global_load_lds(
          (__attribute__((address_space(1))) const void*)(s + (size_t)i * 128 * K),
          (__attribute__((address_space(3))) void*)(&lds[sb + wid * 512 + i * 4096]),
          16, 0, 0);
  };
  auto gfrag = [&](int nf, int s) -> bf16x8 {
    return *(const bf16x8*)&Bf[((size_t)(nfg0 + nf) * NS + s) * 512 + (lane << 3)];
  };

  f32x4 acc[8][4];
#pragma unroll
  for (int i = 0; i < 8; ++i)
#pragma unroll
    for (int n = 0; n < 4; ++n) acc[i][n] = f32x4{0.f, 0.f, 0.f, 0.f};

  int sb0 = 0, sb1 = 8192, sb2 = 16384;
  bf16x8 B0[4], B1[4];

  // prologue: slabs 0,1 in flight (4 ops) + B-frags for step 0 (4 ops)
  stageA(sb0, 0);
  stageA(sb1, 1);
#pragma unroll
  for (int n = 0; n < 4; ++n) B0[n] = gfrag(n, 0);

#define STEP(BC, BG, S)                                                        \
  do {                                                                         \
    asm volatile("s_waitcnt vmcnt(6)" ::: "memory");                           \
    __builtin_amdgcn_s_barrier();                                              \
    stageA(sb2, ((S) + 2 < NS) ? (S) + 2 : 0);                                 \
    const int sg_ = ((S) + 1 < NS) ? (S) + 1 : 0;                              \
    _Pragma("unroll")                                                          \
    for (int n = 0; n < 4; ++n) BG[n] = gfrag(n, sg_);                         \
    bf16x8 a_[8];                                                              \
    _Pragma("unroll")                                                          \
    for (int m = 0; m < 8; ++m)                                                \
      a_[m] = *(const bf16x8*)&lds[sb0 + (wmL + m * 16 + lr) * 32 + rslot];    \
    __builtin_amdgcn_s_setprio(1);                                             \
    _Pragma("unroll")                                                          \
    for (int m = 0; m < 8; ++m)                                                \
      _Pragma("unroll")                                                        \
      for (int n = 0; n < 4; ++n)                                              \
        acc[m][n] = __builtin_amdgcn_mfma_f32_16x16x32_bf16(a_[m], BC[n],      \
                                                            acc[m][n], 0, 0, 0); \
    __builtin_amdgcn_s_setprio(0);                                             \
    int t_ = sb0; sb0 = sb1; sb1 = sb2; sb2 = t_;                              \
  } while (0)

  for (int it = 0; it < NS / 2; ++it) {
    STEP(B0, B1, 2 * it);
    STEP(B1, B0, 2 * it + 1);
  }
#undef STEP

  // drain wrapped staging DMAs before LDS dealloc / kernel end
  asm volatile("s_waitcnt vmcnt(0)" ::: "memory");
  __builtin_amdgcn_s_barrier();

  // epilogue: C/D layout col = lane&15, row = (lane>>4)*4 + j
#pragma unroll
  for (int nf = 0; nf < 4; ++nf) {
    const int col = bn + wnL + nf * 16 + lr;
    const float bv = bias[col];
#pragma unroll
    for (int mf = 0; mf < 8; ++mf) {
      const int row = bm + wmL + mf * 16 + lk * 4;
#pragma unroll
      for (int j = 0; j < 4; ++j)
        C[(size_t)(row + j) * N + col] = acc[mf][nf][j] + bv;
    }
  }
}

extern "C" void kernel_launch(void* const* d_in, const int* in_sizes, int n_in,
                              void* d_out, int out_size, void* d_ws, size_t ws_size,
                              hipStream_t stream) {
  const float* x  = (const float*)d_in[0];
  const float* w  = (const float*)d_in[1];
  const float* lA = (const float*)d_in[2];
  const float* lB = (const float*)d_in[3];
  const float* bs = (const float*)d_in[4];
  float* out = (float*)d_out;

  const int DOUT = in_sizes[4];              // 4096
  const int DIN  = in_sizes[1] / DOUT;       // 4096
  const int M    = in_sizes[0] / DIN;        // 8192

  u16* Xb = (u16*)d_ws;                      // M*DIN bf16 row-major
  u16* Wf = Xb + (size_t)M * DIN;            // DOUT*DIN bf16, frag-packed

  const int n4 = (M * DIN) / 4;
  const int nCvt = 2048;
  const int nW = (DOUT >> 4) * (DIN >> 5) / 4;   // 8192 blocks, 4 frags each
  aux_kernel<<<nCvt + nW, 256, 0, stream>>>((const float4*)x, (u16x4*)Xb, n4, nCvt,
                                            w, lA, lB, Wf, DIN);

  (void)hipFuncSetAttribute((const void*)gemm_kernel,
                            hipFuncAttributeMaxDynamicSharedMemorySize, 49152);

  const int nwg = (M / BM) * (DOUT / BN);    // 512
  gemm_kernel<<<nwg, 512, 49152, stream>>>(Xb, Wf, bs, out, M, DOUT, DIN);
}

// Round 8
// 363.792 us; speedup vs baseline: 1.0329x; 1.0269x over previous
//
#include <hip/hip_runtime.h>
#include <hip/hip_bf16.h>
#include <stdint.h>

typedef unsigned short u16;
typedef u16 u16x4 __attribute__((ext_vector_type(4)));
typedef short bf16x8 __attribute__((ext_vector_type(8)));
typedef float f32x4 __attribute__((ext_vector_type(4)));

__device__ __forceinline__ u16 f2bf(float f) {
  union { float f; uint32_t u; } v; v.f = f;
  uint32_t u = v.u;
  return (u16)((u + 0x7fffu + ((u >> 16) & 1u)) >> 16);
}

// ---------------- fused aux: x fp32->bf16  +  W_eff = W + 2*(B@A) -> bf16 ----------------
__global__ __launch_bounds__(256) void aux_kernel(
    const float4* __restrict__ x, u16x4* __restrict__ xb, int n4, int nCvt,
    const float* __restrict__ W, const float* __restrict__ A,
    const float* __restrict__ Bl, u16* __restrict__ Wout, int DIN) {
  if ((int)blockIdx.x < nCvt) {
    int i = blockIdx.x * 256 + threadIdx.x;
    const int stride = nCvt * 256;
    for (; i < n4; i += stride) {
      float4 v = x[i];
      u16x4 o;
      o.x = f2bf(v.x); o.y = f2bf(v.y); o.z = f2bf(v.z); o.w = f2bf(v.w);
      xb[i] = o;
    }
  } else {
    const int n = blockIdx.x - nCvt;
    float bv[16];
#pragma unroll
    for (int r = 0; r < 16; ++r) bv[r] = 2.0f * Bl[n * 16 + r];
    const int iters = DIN / (256 * 4);
    for (int c = 0; c < iters; ++c) {
      const int k = (c * 256 + (int)threadIdx.x) * 4;
      float4 wv = *(const float4*)&W[(size_t)n * DIN + k];
#pragma unroll
      for (int r = 0; r < 16; ++r) {
        const float4 av = *(const float4*)&A[(size_t)r * DIN + k];
        wv.x += bv[r] * av.x;
        wv.y += bv[r] * av.y;
        wv.z += bv[r] * av.z;
        wv.w += bv[r] * av.w;
      }
      u16x4 o;
      o.x = f2bf(wv.x); o.y = f2bf(wv.y); o.z = f2bf(wv.z); o.w = f2bf(wv.w);
      *(u16x4*)&Wout[(size_t)n * DIN + k] = o;
    }
  }
}

// ---------------- 256x256 bf16 GEMM: frag-contiguous LDS, 8-phase m201 ledger ----------------
// C[M][N] = X[M][K] @ Weff[N][K]^T + bias. 8 waves (2M x 4N), wave out 128x64.
// K-tile = 64 (2 ksub planes of 32). LDS frag-packed: plane(op,par,ks) = 16 frags x 512 u16;
// frag fid holds rows fid*16..+15 x 32 k, lane l at byte l*16 (= exact MFMA fragment).
// ds_read = single shared vaddr + offset:imm (no per-read addr VALU, contiguous 1KB burst).
// 8 phases / 2 K-tiles (par 0 then 1). Per phase: {ds_reads (12/4/8/0); stage 1 half-tile
// (2 gloads); BAR; lgkm0; setprio1; 16 MFMA; setprio0; BAR}. vmcnt(4) gates only at end of
// ph3 (K-tile 2i+1 resident) and ph7 (K-tile 2i+2 resident). FIFO ledger audited; staging
// always lands in buffers whose last reader drained at an earlier lgkm0+BAR.
#define BM 256
#define BN 256

__global__ __launch_bounds__(512, 2) void gemm_kernel(
    const u16* __restrict__ A, const u16* __restrict__ B,
    const float* __restrict__ bias, float* __restrict__ C,
    int M, int N, int K) {
  extern __shared__ u16 lds[];   // 131072 bytes

  const int tid  = threadIdx.x;
  const int lane = tid & 63;
  const int wid  = tid >> 6;

  // XCD-aware block swizzle (nwg % 8 == 0 by launch)
  const int nwg = gridDim.x;
  const int cpx = nwg >> 3;
  const int f   = ((int)blockIdx.x & 7) * cpx + ((int)blockIdx.x >> 3);
  const int nbx = N / BN;
  const int bx = f % nbx, by = f / nbx;
  const int bm = by * BM, bn = bx * BN;

  const int wmL = (wid >> 2) * 128;
  const int wnL = (wid & 3) * 64;
  const int lr  = lane & 15;
  const int lk  = lane >> 4;

  // frag-read base vaddrs (include wave frag base; plane/frag via constant offsets)
  u16* const avp = &lds[lane * 8 + ((wid >> 2) * 8) * 512];
  u16* const bvp = &lds[32768 + lane * 8 + ((wid & 3) * 4) * 512];

  auto ldA = [&](int par, int ks, int mf) -> bf16x8 {
    return *(const bf16x8*)(avp + (par * 2 + ks) * 8192 + mf * 512);
  };
  auto ldB = [&](int par, int ks, int nf) -> bf16x8 {
    return *(const bf16x8*)(bvp + (par * 2 + ks) * 8192 + nf * 512);
  };

  // staging sources: thread covers frag fid = half*8 + wid, lane l -> row fid*16+(l&15),
  // k-group (l>>4)*8. Dest is linear (frag-contiguous), src is per-lane (rule #21).
  const int skoff = lk << 3;
  const u16* gA0 = A + (size_t)(bm + wid * 16 + lr) * K + skoff;          // half 0
  const u16* gA1 = A + (size_t)(bm + 128 + wid * 16 + lr) * K + skoff;    // half 1
  const u16* gB0 = B + (size_t)(bn + wid * 16 + lr) * K + skoff;
  const u16* gB1 = B + (size_t)(bn + 128 + wid * 16 + lr) * K + skoff;

#define STG(gsrc, opbase, par, half, kt)                                          \
  do {                                                                            \
    __builtin_amdgcn_global_load_lds(                                             \
        (__attribute__((address_space(1))) const void*)((gsrc) + (size_t)(kt)*64),\
        (__attribute__((address_space(3))) void*)(                                \
            &lds[(opbase) + ((par)*2 + 0)*8192 + ((half)*8 + wid)*512]), 16, 0, 0);\
    __builtin_amdgcn_global_load_lds(                                             \
        (__attribute__((address_space(1))) const void*)((gsrc) + (size_t)(kt)*64 + 32),\
        (__attribute__((address_space(3))) void*)(                                \
            &lds[(opbase) + ((par)*2 + 1)*8192 + ((half)*8 + wid)*512]), 16, 0, 0);\
  } while (0)
#define STG_A(par, half, kt) STG((half) ? gA1 : gA0, 0, par, half, kt)
#define STG_B(par, half, kt) STG((half) ? gB1 : gB0, 32768, par, half, kt)

#define BAR()   __builtin_amdgcn_s_barrier()
#define LGKM0() asm volatile("s_waitcnt lgkmcnt(0)" ::: "memory")
#define LGKM8() asm volatile("s_waitcnt lgkmcnt(8)" ::: "memory")
#define VM4()   asm volatile("s_waitcnt vmcnt(4)" ::: "memory")

#define MFMA16(MB, NB, B0, B1)                                                    \
  __builtin_amdgcn_s_setprio(1);                                                  \
  _Pragma("unroll")                                                               \
  for (int m = 0; m < 4; ++m)                                                     \
    _Pragma("unroll")                                                             \
    for (int n = 0; n < 2; ++n)                                                   \
      acc[(MB) + m][(NB) + n] = __builtin_amdgcn_mfma_f32_16x16x32_bf16(          \
          aA0[m], B0[n], acc[(MB) + m][(NB) + n], 0, 0, 0);                       \
  _Pragma("unroll")                                                               \
  for (int m = 0; m < 4; ++m)                                                     \
    _Pragma("unroll")                                                             \
    for (int n = 0; n < 2; ++n)                                                   \
      acc[(MB) + m][(NB) + n] = __builtin_amdgcn_mfma_f32_16x16x32_bf16(          \
          aA1[m], B1[n], acc[(MB) + m][(NB) + n], 0, 0, 0);                       \
  __builtin_amdgcn_s_setprio(0)

  f32x4 acc[8][4];
#pragma unroll
  for (int i = 0; i < 8; ++i)
#pragma unroll
    for (int n = 0; n < 4; ++n) acc[i][n] = f32x4{0.f, 0.f, 0.f, 0.f};

  const int NT = K >> 6;   // 64 K-tiles
  // prologue: K-tile 0 (8 ops), then B(1) (4 ops); gate leaves B(1) in flight
  STG_A(0, 0, 0); STG_A(0, 1, 0); STG_B(0, 0, 0); STG_B(0, 1, 0);
  STG_B(1, 0, 1); STG_B(1, 1, 1);
  VM4(); BAR();

  bf16x8 aA0[4], aA1[4], b0_0[2], b0_1[2], b1_0[2], b1_1[2];

  for (int i = 0; i < NT / 2; ++i) {
    const int k1  = 2 * i + 1;
    const int kt2 = (2 * i + 2 < NT) ? 2 * i + 2 : 0;   // wrap keeps vmcnt uniform
    const int kt3 = (2 * i + 3 < NT) ? 2 * i + 3 : 0;

    // ---- ph0 (par0): m0-3 x n0-1, 12 reads ----
#pragma unroll
    for (int n = 0; n < 2; ++n) { b0_0[n] = ldB(0, 0, n); b0_1[n] = ldB(0, 1, n); }
#pragma unroll
    for (int m = 0; m < 4; ++m) { aA0[m] = ldA(0, 0, m); aA1[m] = ldA(0, 1, m); }
    STG_A(1, 0, k1);
    LGKM8(); BAR(); LGKM0();
    MFMA16(0, 0, b0_0, b0_1);
    BAR();

    // ---- ph1 (par0): m0-3 x n2-3, 4 reads ----
#pragma unroll
    for (int n = 0; n < 2; ++n) { b1_0[n] = ldB(0, 0, 2 + n); b1_1[n] = ldB(0, 1, 2 + n); }
    STG_A(1, 1, k1);
    BAR(); LGKM0();
    MFMA16(0, 2, b1_0, b1_1);
    BAR();

    // ---- ph2 (par0): m4-7 x n0-1, 8 reads ----
#pragma unroll
    for (int m = 0; m < 4; ++m) { aA0[m] = ldA(0, 0, 4 + m); aA1[m] = ldA(0, 1, 4 + m); }
    STG_B(0, 0, kt2);
    BAR(); LGKM0();
    MFMA16(4, 0, b0_0, b0_1);
    BAR();

    // ---- ph3 (par0): m4-7 x n2-3, 0 reads; gate K-tile k1 ----
    STG_B(0, 1, kt2);
    BAR(); LGKM0();
    MFMA16(4, 2, b1_0, b1_1);
    VM4(); BAR();

    // ---- ph4 (par1): m0-3 x n0-1, 12 reads ----
#pragma unroll
    for (int n = 0; n < 2; ++n) { b0_0[n] = ldB(1, 0, n); b0_1[n] = ldB(1, 1, n); }
#pragma unroll
    for (int m = 0; m < 4; ++m) { aA0[m] = ldA(1, 0, m); aA1[m] = ldA(1, 1, m); }
    STG_A(0, 0, kt2);
    LGKM8(); BAR(); LGKM0();
    MFMA16(0, 0, b0_0, b0_1);
    BAR();

    // ---- ph5 (par1): m0-3 x n2-3, 4 reads ----
#pragma unroll
    for (int n = 0; n < 2; ++n) { b1_0[n] = ldB(1, 0, 2 + n); b1_1[n] = ldB(1, 1, 2 + n); }
    STG_A(0, 1, kt2);
    BAR(); LGKM0();
    MFMA16(0, 2, b1_0, b1_1);
    BAR();

    // ---- ph6 (par1): m4-7 x n0-1, 8 reads ----
#pragma unroll
    for (int m = 0; m < 4; ++m) { aA0[m] = ldA(1, 0, 4 + m); aA1[m] = ldA(1, 1, 4 + m); }
    STG_B(1, 0, kt3);
    BAR(); LGKM0();
    MFMA16(4, 0, b0_0, b0_1);
    BAR();

    // ---- ph7 (par1): m4-7 x n2-3, 0 reads; gate K-tile kt2 ----
    STG_B(1, 1, kt3);
    BAR(); LGKM0();
    MFMA16(4, 2, b1_0, b1_1);
    VM4(); BAR();
  }

  // drain wrapped staging DMAs before LDS dealloc / kernel end
  asm volatile("s_waitcnt vmcnt(0)" ::: "memory");
  __builtin_amdgcn_s_barrier();

  // epilogue: C/D layout col = lane&15, row = (lane>>4)*4 + j (r5-verified)
#pragma unroll
  for (int nf = 0; nf < 4; ++nf) {
    const int col = bn + wnL + nf * 16 + lr;
    const float bv = bias[col];
#pragma unroll
    for (int mf = 0; mf < 8; ++mf) {
      const int row = bm + wmL + mf * 16 + lk * 4;
#pragma unroll
      for (int j = 0; j < 4; ++j)
        C[(size_t)(row + j) * N + col] = acc[mf][nf][j] + bv;
    }
  }
#undef STG
#undef STG_A
#undef STG_B
#undef BAR
#undef LGKM0
#undef LGKM8
#undef VM4
#undef MFMA16
}

extern "C" void kernel_launch(void* const* d_in, const int* in_sizes, int n_in,
                              void* d_out, int out_size, void* d_ws, size_t ws_size,
                              hipStream_t stream) {
  const float* x  = (const float*)d_in[0];
  const float* w  = (const float*)d_in[1];
  const float* lA = (const float*)d_in[2];
  const float* lB = (const float*)d_in[3];
  const float* bs = (const float*)d_in[4];
  float* out = (float*)d_out;

  const int DOUT = in_sizes[4];              // 4096
  const int DIN  = in_sizes[1] / DOUT;       // 4096
  const int M    = in_sizes[0] / DIN;        // 8192

  u16* Xb = (u16*)d_ws;                      // M*DIN bf16
  u16* Wb = Xb + (size_t)M * DIN;            // DOUT*DIN bf16

  const int n4 = (M * DIN) / 4;
  const int nCvt = 2048;
  aux_kernel<<<nCvt + DOUT, 256, 0, stream>>>((const float4*)x, (u16x4*)Xb, n4, nCvt,
                                              w, lA, lB, Wb, DIN);

  (void)hipFuncSetAttribute((const void*)gemm_kernel,
                            hipFuncAttributeMaxDynamicSharedMemorySize, 131072);

  const int nwg = (M / BM) * (DOUT / BN);    // 512
  gemm_kernel<<<nwg, 512, 131072, stream>>>(Xb, Wb, bs, out, M, DOUT, DIN);
}